// Round 9
// baseline (41.637 us; speedup 1.0000x reference)
//
#include <hip/hip_runtime.h>

#define B_ 2048
#define V_ 2048
#define C_ 512
#define M_ 8
#define H_ 16
#define GATH (V_ - C_)        // 1536 gatherable cols per row

__device__ __forceinline__ float fast_exp2(float x) { return __builtin_amdgcn_exp2f(x); }
__device__ __forceinline__ float fast_rcp(float x)  { return __builtin_amdgcn_rcpf(x); }

#define K_SCALE 2.885390081777927f      // 2*log2(e): tanh(x) = 1 - 2*rcp(exp2(K*x)+1)
#define LOG2E   1.4426950408889634f

// One block = ONE row, 512 threads: thread c computes col c; threads 0..383
// also copy+stage cols [512,2048) (96 B each). All global loads issue before
// the barrier; after it, only LDS gathers + compute.
__global__ __launch_bounds__(512) void grad_attn_kernel(
    const float* __restrict__ preds,
    const int*   __restrict__ mask_ids,
    const float* __restrict__ W1,
    const float* __restrict__ b1,
    const float* __restrict__ W2,
    float*       __restrict__ out)
{
    __shared__ float smem[GATH];   // 6 KB

    const int c   = threadIdx.x;          // 0..511 == column
    const int row = blockIdx.x;
    const float* rowp = preds + (size_t)row * V_;

    // ---- independent global loads, all issued up front ----
    const float ha = rowp[c];             // coalesced

    // copy + stage cols [C_, V_): 384 float4 by threads 0..383
    float4 cp;
    if (c < GATH / 4) {
        cp = reinterpret_cast<const float4*>(rowp + C_)[c];
        reinterpret_cast<float4*>(out + (size_t)row * V_ + C_)[c] = cp;
        *reinterpret_cast<float4*>(&smem[4 * c]) = cp;
    }

    // weights: compute pa[h] immediately so w1a/b1 registers die early
    float pa[H_], w1b[H_], w2n[H_];
    {
        const float4* W1v = reinterpret_cast<const float4*>(W1 + (size_t)c * 2 * H_);
        const float4* b1v = reinterpret_cast<const float4*>(b1 + (size_t)c * H_);
        const float4* W2v = reinterpret_cast<const float4*>(W2 + (size_t)c * H_);
        #pragma unroll
        for (int i = 0; i < H_ / 4; ++i) {
            float4 a = W1v[i], bk = W1v[H_ / 4 + i], bv = b1v[i], wv = W2v[i];
            // pa = K*(ha*w1a + b1)
            pa[4*i+0] = fmaf(ha, a.x, bv.x) * K_SCALE;
            pa[4*i+1] = fmaf(ha, a.y, bv.y) * K_SCALE;
            pa[4*i+2] = fmaf(ha, a.z, bv.z) * K_SCALE;
            pa[4*i+3] = fmaf(ha, a.w, bv.w) * K_SCALE;
            w1b[4*i+0] = bk.x * K_SCALE; w1b[4*i+1] = bk.y * K_SCALE;
            w1b[4*i+2] = bk.z * K_SCALE; w1b[4*i+3] = bk.w * K_SCALE;
            w2n[4*i+0] = -2.0f * wv.x;   w2n[4*i+1] = -2.0f * wv.y;
            w2n[4*i+2] = -2.0f * wv.z;   w2n[4*i+3] = -2.0f * wv.w;
        }
    }

    int midx[M_];
    {
        const int4* mi = reinterpret_cast<const int4*>(mask_ids + (size_t)c * M_);
        int4 a = mi[0], b = mi[1];
        midx[0] = a.x - C_; midx[1] = a.y - C_; midx[2] = a.z - C_; midx[3] = a.w - C_;
        midx[4] = b.x - C_; midx[5] = b.y - C_; midx[6] = b.z - C_; midx[7] = b.w - C_;
    }

    __syncthreads();

    // ---- LDS gathers ----
    float hm[M_];
    #pragma unroll
    for (int m = 0; m < M_; ++m) hm[m] = smem[midx[m]];

    // ---- compute (R2's proven inner loop) ----
    float sc[M_];
    #pragma unroll
    for (int m = 0; m < M_; ++m) sc[m] = 0.0f;

    #pragma unroll
    for (int h = 0; h < H_; ++h) {
        const float pah = pa[h];
        const float wb  = w1b[h];
        const float w2h = w2n[h];
        #pragma unroll
        for (int m = 0; m < M_; ++m) {
            float e = fast_exp2(fmaf(hm[m], wb, pah));
            sc[m] = fmaf(fast_rcp(e + 1.0f), w2h, sc[m]);
        }
    }

    // softmax over M (uniform base term cancels; |sc| small -> exp2 safe)
    float ex[M_], sum = 0.0f, ws = 0.0f;
    #pragma unroll
    for (int m = 0; m < M_; ++m) {
        ex[m] = fast_exp2(sc[m] * LOG2E);
        sum += ex[m];
    }
    #pragma unroll
    for (int m = 0; m < M_; ++m) ws = fmaf(ex[m], hm[m], ws);
    float corrected = fmaxf(ha, fmaf(ws, fast_rcp(sum), 1e-6f));
    out[(size_t)row * V_ + c] = corrected;
}

extern "C" void kernel_launch(void* const* d_in, const int* in_sizes, int n_in,
                              void* d_out, int out_size, void* d_ws, size_t ws_size,
                              hipStream_t stream) {
    const float* preds    = (const float*)d_in[0];
    const int*   mask_ids = (const int*)d_in[2];
    const float* W1       = (const float*)d_in[3];
    const float* b1       = (const float*)d_in[4];
    const float* W2       = (const float*)d_in[5];
    float* out = (float*)d_out;

    dim3 grid(B_);           // 2048 blocks = one per row
    dim3 block(512);
    grad_attn_kernel<<<grid, block, 0, stream>>>(preds, mask_ids, W1, b1, W2, out);
}

// Round 10
// 36.292 us; speedup vs baseline: 1.1473x; 1.1473x over previous
//
#include <hip/hip_runtime.h>

#define B_ 2048
#define V_ 2048
#define C_ 512
#define M_ 8
#define H_ 16
#define NB 2            // rows per compute block, fused in one loop
#define CHUNK 256       // columns per compute block == blockDim.x
#define NCOMPUTE ((C_ / CHUNK) * (B_ / NB))   // 2048 compute blocks
#define NCOPY (B_ / 2)                        // 1024 copy blocks, 2 rows each

__device__ __forceinline__ float fast_exp2(float x) { return __builtin_amdgcn_exp2f(x); }
__device__ __forceinline__ float fast_rcp(float x)  { return __builtin_amdgcn_rcpf(x); }

#define K_SCALE 2.885390081777927f      // 2*log2(e): tanh(x) = 1 - 2*rcp(exp2(K*x)+1)
#define LOG2E   1.4426950408889634f

__global__ __launch_bounds__(256) void grad_attn_kernel(
    const float* __restrict__ preds,
    const int*   __restrict__ mask_ids,
    const float* __restrict__ W1,
    const float* __restrict__ b1,
    const float* __restrict__ W2,
    float*       __restrict__ out)
{
    const int tid = threadIdx.x;
    const int bi  = blockIdx.x;

    if (bi >= NCOMPUTE) {
        // ---- pure copy region: cols [C_, V_) of 2 rows ----
        const int r0 = (bi - NCOMPUTE) * 2;
        #pragma unroll
        for (int r = 0; r < 2; ++r) {
            const float4* src = reinterpret_cast<const float4*>(preds + (size_t)(r0 + r) * V_ + C_);
            float4*       dst = reinterpret_cast<float4*>(out + (size_t)(r0 + r) * V_ + C_);
            #pragma unroll
            for (int j = tid; j < (V_ - C_) / 4; j += 256) dst[j] = src[j];
        }
        return;
    }

    const int chunk  = bi & 1;
    const int rowgrp = bi >> 1;
    const int b0 = rowgrp * NB;
    const int c  = chunk * CHUNK + tid;

    // ---- ALL global loads hoisted up front: weights, indices, both rows ----
    int midx[M_];
    {
        const int4* mi = reinterpret_cast<const int4*>(mask_ids + (size_t)c * M_);
        int4 a = mi[0], b = mi[1];
        midx[0] = a.x; midx[1] = a.y; midx[2] = a.z; midx[3] = a.w;
        midx[4] = b.x; midx[5] = b.y; midx[6] = b.z; midx[7] = b.w;
    }

    float w1a[H_], w1b[H_], bb[H_], w2n[H_];
    {
        const float4* W1v = reinterpret_cast<const float4*>(W1 + (size_t)c * 2 * H_);
        const float4* b1v = reinterpret_cast<const float4*>(b1 + (size_t)c * H_);
        const float4* W2v = reinterpret_cast<const float4*>(W2 + (size_t)c * H_);
        #pragma unroll
        for (int i = 0; i < H_ / 4; ++i) {
            float4 a = W1v[i], bk = W1v[H_ / 4 + i], bv = b1v[i], wv = W2v[i];
            w1a[4*i+0] = a.x * K_SCALE;  w1a[4*i+1] = a.y * K_SCALE;
            w1a[4*i+2] = a.z * K_SCALE;  w1a[4*i+3] = a.w * K_SCALE;
            w1b[4*i+0] = bk.x * K_SCALE; w1b[4*i+1] = bk.y * K_SCALE;
            w1b[4*i+2] = bk.z * K_SCALE; w1b[4*i+3] = bk.w * K_SCALE;
            bb[4*i+0]  = bv.x * K_SCALE; bb[4*i+1]  = bv.y * K_SCALE;
            bb[4*i+2]  = bv.z * K_SCALE; bb[4*i+3]  = bv.w * K_SCALE;
            w2n[4*i+0] = -2.0f * wv.x;   w2n[4*i+1] = -2.0f * wv.y;
            w2n[4*i+2] = -2.0f * wv.z;   w2n[4*i+3] = -2.0f * wv.w;
        }
    }

    // both rows' ha + gathers issued before ANY compute
    const float* row0 = preds + (size_t)b0 * V_;
    const float* row1 = row0 + V_;
    float ha[NB];
    ha[0] = row0[c];
    ha[1] = row1[c];
    float hm[NB][M_];
    #pragma unroll
    for (int m = 0; m < M_; ++m) hm[0][m] = row0[midx[m]];
    #pragma unroll
    for (int m = 0; m < M_; ++m) hm[1][m] = row1[midx[m]];

    // ---- fused 2-row compute: 16 independent trans chains per h ----
    float sc[NB][M_];
    #pragma unroll
    for (int r = 0; r < NB; ++r)
        #pragma unroll
        for (int m = 0; m < M_; ++m) sc[r][m] = 0.0f;

    #pragma unroll
    for (int h = 0; h < H_; ++h) {
        const float wa  = w1a[h];
        const float wb  = w1b[h];
        const float bh  = bb[h];
        const float w2h = w2n[h];
        #pragma unroll
        for (int r = 0; r < NB; ++r) {
            const float pa = fmaf(ha[r], wa, bh);
            #pragma unroll
            for (int m = 0; m < M_; ++m) {
                float e = fast_exp2(fmaf(hm[r][m], wb, pa));
                sc[r][m] = fmaf(fast_rcp(e + 1.0f), w2h, sc[r][m]);
            }
        }
    }

    // ---- softmax + output, both rows ----
    #pragma unroll
    for (int r = 0; r < NB; ++r) {
        float ex[M_], sum = 0.0f, ws = 0.0f;
        #pragma unroll
        for (int m = 0; m < M_; ++m) {
            ex[m] = fast_exp2(sc[r][m] * LOG2E);
            sum += ex[m];
        }
        #pragma unroll
        for (int m = 0; m < M_; ++m) ws = fmaf(ex[m], hm[r][m], ws);
        float corrected = fmaxf(ha[r], fmaf(ws, fast_rcp(sum), 1e-6f));
        out[(size_t)(b0 + r) * V_ + c] = corrected;
    }
}

extern "C" void kernel_launch(void* const* d_in, const int* in_sizes, int n_in,
                              void* d_out, int out_size, void* d_ws, size_t ws_size,
                              hipStream_t stream) {
    const float* preds    = (const float*)d_in[0];
    const int*   mask_ids = (const int*)d_in[2];
    const float* W1       = (const float*)d_in[3];
    const float* b1       = (const float*)d_in[4];
    const float* W2       = (const float*)d_in[5];
    float* out = (float*)d_out;

    dim3 grid(NCOMPUTE + NCOPY);
    dim3 block(256);
    grad_attn_kernel<<<grid, block, 0, stream>>>(preds, mask_ids, W1, b1, W2, out);
}